// Round 1
// baseline (204.218 us; speedup 1.0000x reference)
//
#include <hip/hip_runtime.h>

// Dilate = 5x5 per-channel max filter, SAME padding, (64,384,384,3) f32.
// v2: restore the intended 16-deep load pipeline.
//   - __launch_bounds__(256, 4): 128-VGPR budget so raw[16] float4 (64 VGPR)
//     stays in registers and all 16 row-loads are genuinely in flight.
//     (v1 had VGPR_Count=56 -> regalloc sank the loads -> latency-serialized,
//      2.6 TB/s on a 6.3 TB/s-capable access pattern.)
//   - vertical-first separable max: 12 shuffle rows instead of 16.
//   - bijective XCD swizzle (2560%8==0): each XCD owns 8 whole images ->
//     band-halo re-reads hit its private L2.
//   - nontemporal output stores: write-once stream, don't evict input halo.
//   grid = 64 batch x 8 band-groups x 5 column-strips; 256-thr blocks.
//   Wave w handles band grp*4+w: RB=12 output rows (16 input rows incl halo).
//   Lane owns f4-col strip*60 - 2 + lane (strips overlap 4 for h-halo).

#define Bn 64
#define H 384
#define ROWF 1152            // floats per image row (384*3)
#define ROWBYTES (ROWF * 4)
#define WF4 288              // float4s per row
#define RB 12                // output rows per wave
#define NLOAD (RB + 4)       // 16 input rows per wave
#define GROUPS 8             // (384/12)=32 bands / 4 waves per block
#define STRIPS 5             // 5 * 60 = 300 >= 288 output f4 cols
#define SOUT 60
#define NBLK (Bn * GROUPS * STRIPS)   // 2560 (divisible by 8 -> simple swizzle ok)
#define NEGINF (-3.402823466e+38f)

typedef float f32x4 __attribute__((ext_vector_type(4)));

__device__ __forceinline__ float4 max4(float4 a, float4 b) {
  return make_float4(fmaxf(a.x, b.x), fmaxf(a.y, b.y),
                     fmaxf(a.z, b.z), fmaxf(a.w, b.w));
}
__device__ __forceinline__ float4 shflup4(float4 v, int d) {
  return make_float4(__shfl_up(v.x, d), __shfl_up(v.y, d),
                     __shfl_up(v.z, d), __shfl_up(v.w, d));
}
__device__ __forceinline__ float4 shfldn4(float4 v, int d) {
  return make_float4(__shfl_down(v.x, d), __shfl_down(v.y, d),
                     __shfl_down(v.z, d), __shfl_down(v.w, d));
}

__global__ __launch_bounds__(256, 4) void dilate5_kernel(
    const float* __restrict__ in, float* __restrict__ out) {
  const int wv = threadIdx.x >> 6;
  const int lane = threadIdx.x & 63;

  // XCD-aware swizzle: consecutive hardware dispatch (round-robin across 8
  // XCDs) maps to 8 contiguous grid chunks -> XCD x owns images 8x..8x+7.
  const int orig = blockIdx.x;
  int t = (orig & 7) * (NBLK / 8) + (orig >> 3);
  const int strip = t % STRIPS; t /= STRIPS;
  const int grp = t % GROUPS;   t /= GROUPS;
  const int b = t;

  const int row0 = (grp * 4 + wv) * RB;
  const int col = strip * SOUT - 2 + lane;          // owned f4 col (may be OOB)
  const bool cvalid = (col >= 0) && (col < WF4);
  const int ccl = col < 0 ? 0 : (col > WF4 - 1 ? WF4 - 1 : col);
  const size_t coff = (size_t)ccl * 16;
  const bool willstore = (lane >= 2) && (lane < 62) && (col < WF4);

  const float4 ninf = make_float4(NEGINF, NEGINF, NEGINF, NEGINF);
  const char* __restrict__ imgb = (const char*)in + (size_t)b * H * ROWBYTES;
  char* __restrict__ outb = (char*)out + (size_t)b * H * ROWBYTES;

  // ---- Phase 1: issue ALL row loads back-to-back (16 KB in flight/wave) ----
  float4 raw[NLOAD];
#pragma unroll
  for (int j = 0; j < NLOAD; ++j) {
    int gh = row0 - 2 + j;
    int ghc = gh < 0 ? 0 : (gh > H - 1 ? H - 1 : gh);   // clamp address
    raw[j] = *reinterpret_cast<const float4*>(imgb + (size_t)ghc * ROWBYTES + coff);
  }

  // Row-validity masking (wave-uniform: only first/last band affected).
  if (row0 == 0)      { raw[0] = ninf; raw[1] = ninf; }
  if (row0 == H - RB) { raw[NLOAD - 2] = ninf; raw[NLOAD - 1] = ninf; }

  // ---- Phase 2: vertical-first; one shuffle pass per OUTPUT row (12) ------
#pragma unroll
  for (int i = 0; i < RB; ++i) {
    const int o = row0 + i;
    // vertical 5-max over raw rows i..i+4 (pure VALU, no cross-lane)
    float4 v = max4(max4(max4(raw[i], raw[i + 1]), max4(raw[i + 2], raw[i + 3])),
                    raw[i + 4]);
    if (!cvalid) v = ninf;           // invalid col lanes present -inf to nbrs

    // horizontal 5-max via cross-lane shuffles (channel stride 3)
    float4 A = shflup4(v, 2);
    float4 Bv = shflup4(v, 1);
    float4 D = shfldn4(v, 1);
    float4 E = shfldn4(v, 2);
    float4 h;
    h.x = fmaxf(fmaxf(fmaxf(A.z, Bv.y), fmaxf(v.x, v.w)), D.z);
    h.y = fmaxf(fmaxf(fmaxf(A.w, Bv.z), fmaxf(v.y, D.x)), D.w);
    h.z = fmaxf(fmaxf(fmaxf(Bv.x, Bv.w), fmaxf(v.z, D.y)), E.x);
    h.w = fmaxf(fmaxf(fmaxf(Bv.y, v.x), fmaxf(v.w, D.z)), E.y);

    if (willstore) {
      f32x4 hv; hv.x = h.x; hv.y = h.y; hv.z = h.z; hv.w = h.w;
      __builtin_nontemporal_store(
          hv, reinterpret_cast<f32x4*>(outb + (size_t)o * ROWBYTES + coff));
    }
  }
}

extern "C" void kernel_launch(void* const* d_in, const int* in_sizes, int n_in,
                              void* d_out, int out_size, void* d_ws, size_t ws_size,
                              hipStream_t stream) {
  const float* images = (const float*)d_in[0];
  float* out = (float*)d_out;
  dilate5_kernel<<<NBLK, 256, 0, stream>>>(images, out);
}

// Round 2
// 203.388 us; speedup vs baseline: 1.0041x; 1.0041x over previous
//
#include <hip/hip_runtime.h>

// Dilate = 5x5 per-channel max filter, SAME padding, (64,384,384,3) f32.
// v3: actually force the 16-deep load pipeline.
//   v2 post-mortem: VGPR_Count=52 proved the machine scheduler SANK the
//   raw[16] loads into the consume loop (~5 rows live, ~1 load in flight,
//   in-order vmcnt => latency-serialized, 2.3 TB/s). launch_bounds only
//   caps registers; it doesn't forbid sinking.
//   Fix: __builtin_amdgcn_sched_barrier(0) hard fence between the load
//   loop and the consume loop. All 16 float4 loads must issue before the
//   fence -> 16 KB in flight per wave; compiler's own counted
//   s_waitcnt vmcnt(N) drains them in order during consumption.
//   Kept from v2 (verified by counters): XCD swizzle (FETCH 70->55 MB),
//   vertical-first separable max, nontemporal stores.
//   grid = 64 batch x 8 band-groups x 5 column-strips; 256-thr blocks.

#define Bn 64
#define H 384
#define ROWF 1152            // floats per image row (384*3)
#define ROWBYTES (ROWF * 4)
#define WF4 288              // float4s per row
#define RB 12                // output rows per wave
#define NLOAD (RB + 4)       // 16 input rows per wave
#define GROUPS 8             // (384/12)=32 bands / 4 waves per block
#define STRIPS 5             // 5 * 60 = 300 >= 288 output f4 cols
#define SOUT 60
#define NBLK (Bn * GROUPS * STRIPS)   // 2560 (divisible by 8 -> simple swizzle ok)
#define NEGINF (-3.402823466e+38f)

typedef float f32x4 __attribute__((ext_vector_type(4)));

__device__ __forceinline__ float4 max4(float4 a, float4 b) {
  return make_float4(fmaxf(a.x, b.x), fmaxf(a.y, b.y),
                     fmaxf(a.z, b.z), fmaxf(a.w, b.w));
}
__device__ __forceinline__ float4 shflup4(float4 v, int d) {
  return make_float4(__shfl_up(v.x, d), __shfl_up(v.y, d),
                     __shfl_up(v.z, d), __shfl_up(v.w, d));
}
__device__ __forceinline__ float4 shfldn4(float4 v, int d) {
  return make_float4(__shfl_down(v.x, d), __shfl_down(v.y, d),
                     __shfl_down(v.z, d), __shfl_down(v.w, d));
}

__global__ __launch_bounds__(256, 4) void dilate5_kernel(
    const float* __restrict__ in, float* __restrict__ out) {
  const int wv = threadIdx.x >> 6;
  const int lane = threadIdx.x & 63;

  // XCD-aware swizzle: XCD x owns images 8x..8x+7 -> band-halo re-reads
  // hit its private L2 (verified: FETCH 70->55 MB in v2).
  const int orig = blockIdx.x;
  int t = (orig & 7) * (NBLK / 8) + (orig >> 3);
  const int strip = t % STRIPS; t /= STRIPS;
  const int grp = t % GROUPS;   t /= GROUPS;
  const int b = t;

  const int row0 = (grp * 4 + wv) * RB;
  const int col = strip * SOUT - 2 + lane;          // owned f4 col (may be OOB)
  const bool cvalid = (col >= 0) && (col < WF4);
  const int ccl = col < 0 ? 0 : (col > WF4 - 1 ? WF4 - 1 : col);
  const size_t coff = (size_t)ccl * 16;
  const bool willstore = (lane >= 2) && (lane < 62) && (col < WF4);

  const float4 ninf = make_float4(NEGINF, NEGINF, NEGINF, NEGINF);
  const char* __restrict__ imgb = (const char*)in + (size_t)b * H * ROWBYTES;
  char* __restrict__ outb = (char*)out + (size_t)b * H * ROWBYTES;

  // ---- Phase 1: issue ALL 16 row loads back-to-back (16 KB in flight) ----
  float4 raw[NLOAD];
#pragma unroll
  for (int j = 0; j < NLOAD; ++j) {
    int gh = row0 - 2 + j;
    int ghc = gh < 0 ? 0 : (gh > H - 1 ? H - 1 : gh);   // clamp address
    raw[j] = *reinterpret_cast<const float4*>(imgb + (size_t)ghc * ROWBYTES + coff);
  }
  // Hard scheduling fence: nothing below may be hoisted above, no load may
  // sink below. Forces all 16 loads issued here and their 64 dest VGPRs
  // live across this point. Compiler then emits counted vmcnt waits for
  // the in-order drain during consumption.
  __builtin_amdgcn_sched_barrier(0);

  // Row-validity masking (wave-uniform: only first/last band affected).
  if (row0 == 0)      { raw[0] = ninf; raw[1] = ninf; }
  if (row0 == H - RB) { raw[NLOAD - 2] = ninf; raw[NLOAD - 1] = ninf; }

  // ---- Phase 2: vertical-first; one shuffle pass per OUTPUT row (12) ------
#pragma unroll
  for (int i = 0; i < RB; ++i) {
    const int o = row0 + i;
    // vertical 5-max over raw rows i..i+4 (pure VALU, no cross-lane)
    float4 v = max4(max4(max4(raw[i], raw[i + 1]), max4(raw[i + 2], raw[i + 3])),
                    raw[i + 4]);
    if (!cvalid) v = ninf;           // invalid col lanes present -inf to nbrs

    // horizontal 5-max via cross-lane shuffles (channel stride 3)
    float4 A = shflup4(v, 2);
    float4 Bv = shflup4(v, 1);
    float4 D = shfldn4(v, 1);
    float4 E = shfldn4(v, 2);
    float4 h;
    h.x = fmaxf(fmaxf(fmaxf(A.z, Bv.y), fmaxf(v.x, v.w)), D.z);
    h.y = fmaxf(fmaxf(fmaxf(A.w, Bv.z), fmaxf(v.y, D.x)), D.w);
    h.z = fmaxf(fmaxf(fmaxf(Bv.x, Bv.w), fmaxf(v.z, D.y)), E.x);
    h.w = fmaxf(fmaxf(fmaxf(Bv.y, v.x), fmaxf(v.w, D.z)), E.y);

    if (willstore) {
      f32x4 hv; hv.x = h.x; hv.y = h.y; hv.z = h.z; hv.w = h.w;
      __builtin_nontemporal_store(
          hv, reinterpret_cast<f32x4*>(outb + (size_t)o * ROWBYTES + coff));
    }
  }
}

extern "C" void kernel_launch(void* const* d_in, const int* in_sizes, int n_in,
                              void* d_out, int out_size, void* d_ws, size_t ws_size,
                              hipStream_t stream) {
  const float* images = (const float*)d_in[0];
  float* out = (float*)d_out;
  dilate5_kernel<<<NBLK, 256, 0, stream>>>(images, out);
}